// Round 5
// baseline (388.921 us; speedup 1.0000x reference)
//
#include <hip/hip_runtime.h>
#include <hip/hip_cooperative_groups.h>
#include <math.h>

namespace cg = cooperative_groups;

#define DIM 128
#define LN_EPS 1e-5f
#define HB 512      // edge chunks for histogram/scatter passes
#define CAP 2048    // fixed srt capacity per 64-dest bucket (mean 1024, sd 32)
#define SMEM_BYTES 34816   // 34 KB union: gather needs 33.0 KB, gemm 17.0 KB

typedef __attribute__((ext_vector_type(8))) short short8;   // 8 bf16 = 4 VGPR
typedef __attribute__((ext_vector_type(4))) float floatx4;

__device__ __forceinline__ float gelu_exact(float v) {
    return 0.5f * v * (1.0f + erff(v * 0.70710678118654752f));
}
__device__ __forceinline__ float bf2f(unsigned short u) {
    return __uint_as_float(((unsigned)u) << 16);
}
__device__ __forceinline__ short f2bf(float f) {
    unsigned b = __float_as_uint(f);
    return (short)((b + 0x7FFF + ((b >> 16) & 1)) >> 16);  // RNE
}

// ---------------------------------------------------------------------------
// W -> bf16 fragment conversion (one-time, 2048 threads). Fragment-order
// slots so GEMM B-fragments are consecutive 16B loads per lane.
// ---------------------------------------------------------------------------
__global__ __launch_bounds__(256) void wconv_kernel(
    const float* __restrict__ W, short* __restrict__ wfrag)
{
    int c = blockIdx.x * 256 + threadIdx.x;   // 0..2047
    int nrow = ((c >> 8) << 4) | (c & 15);                    // jt*16+nloc
    int kb   = (((c >> 6) & 3) << 5) + (((c >> 4) & 3) << 3); // kq*32+quad*8
    const float* wp = W + nrow * DIM + kb;
    float4 w0 = *(const float4*)wp;
    float4 w1 = *(const float4*)(wp + 4);
    short8 p;
    p[0] = f2bf(w0.x); p[1] = f2bf(w0.y); p[2] = f2bf(w0.z); p[3] = f2bf(w0.w);
    p[4] = f2bf(w1.x); p[5] = f2bf(w1.y); p[6] = f2bf(w1.z); p[7] = f2bf(w1.w);
    *(short8*)&wfrag[c * 8] = p;
}

// ========================= phase device functions ==========================
// Each phase starts with __syncthreads() so the smem union can be re-aliased
// safely across sequential per-block tasks. All control flow around
// __syncthreads is block-uniform.

__device__ __forceinline__ void ph_hist(
    char* smem, int g, const int* __restrict__ col, int* __restrict__ hist,
    int E, int nbkt, int tid)
{
    int* lh = (int*)smem;            // nbkt ints (<= 1024 -> 4 KB)
    __syncthreads();
    for (int b = tid; b < nbkt; b += 256) lh[b] = 0;
    __syncthreads();
    int chunk = (E + HB - 1) / HB;
    int e0 = g * chunk;
    int e1 = e0 + chunk; if (e1 > E) e1 = E;
    for (int e = e0 + tid; e < e1; e += 256)
        atomicAdd(&lh[col[e] >> 6], 1);          // LDS atomic only
    __syncthreads();
    for (int b = tid; b < nbkt; b += 256)
        hist[(size_t)g * nbkt + b] = lh[b];      // coalesced row write
}

__device__ __forceinline__ void ph_gemm(
    char* smem, int gb, const float* __restrict__ x,
    const short8* __restrict__ wf,
    const float* __restrict__ lnw, const float* __restrict__ lnb,
    unsigned short* __restrict__ h16, int n, int tid)
{
    short* axb = (short*)smem;       // 16 KB xn bf16 fragments
    __syncthreads();
    const int n0 = gb * 64;

    // LayerNorm straight from global, 4 threads/node
    {
        int m = tid >> 2, sub = tid & 3;
        int node = n0 + m;
        bool valid = (node < n);
        const float4* xp = (const float4*)(x + (size_t)node * DIM + sub * 32);
        float4 v[8];
        float s = 0.f, ss = 0.f;
        #pragma unroll
        for (int i = 0; i < 8; ++i) {
            v[i] = valid ? xp[i] : make_float4(0.f, 0.f, 0.f, 0.f);
            s  += v[i].x + v[i].y + v[i].z + v[i].w;
            ss += v[i].x * v[i].x + v[i].y * v[i].y + v[i].z * v[i].z + v[i].w * v[i].w;
        }
        s += __shfl_xor(s, 1); ss += __shfl_xor(ss, 1);
        s += __shfl_xor(s, 2); ss += __shfl_xor(ss, 2);
        float mu   = s * (1.0f / 128.0f);
        float var  = ss * (1.0f / 128.0f) - mu * mu;
        float rstd = rsqrtf(var + LN_EPS);

        int mt = m >> 4, mloc = m & 15;
        #pragma unroll
        for (int quad = 0; quad < 4; ++quad) {
            float4 a = v[2 * quad], c4 = v[2 * quad + 1];
            const float4* lw = (const float4*)(lnw + sub * 32 + quad * 8);
            const float4* lb = (const float4*)(lnb + sub * 32 + quad * 8);
            float4 lw0 = lw[0], lw1 = lw[1], lb0 = lb[0], lb1 = lb[1];
            short8 p;
            p[0] = f2bf((a.x  - mu) * rstd * lw0.x + lb0.x);
            p[1] = f2bf((a.y  - mu) * rstd * lw0.y + lb0.y);
            p[2] = f2bf((a.z  - mu) * rstd * lw0.z + lb0.z);
            p[3] = f2bf((a.w  - mu) * rstd * lw0.w + lb0.w);
            p[4] = f2bf((c4.x - mu) * rstd * lw1.x + lb1.x);
            p[5] = f2bf((c4.y - mu) * rstd * lw1.y + lb1.y);
            p[6] = f2bf((c4.z - mu) * rstd * lw1.z + lb1.z);
            p[7] = f2bf((c4.w - mu) * rstd * lw1.w + lb1.w);
            int slot = mt * 256 + sub * 64 + quad * 16 + mloc;
            *(short8*)&axb[slot * 8] = p;
        }
    }
    __syncthreads();

    // MFMA: wave w -> m-tile w, all 8 j-tiles; B fragments from global (L1/L2)
    const int w    = tid >> 6;
    const int lane = tid & 63;

    short8 afrag[4];
    #pragma unroll
    for (int kq = 0; kq < 4; ++kq)
        afrag[kq] = *(const short8*)&axb[(w * 256 + kq * 64 + lane) * 8];

    floatx4 acc[8];
    #pragma unroll
    for (int jt = 0; jt < 8; ++jt) acc[jt] = (floatx4){0.f, 0.f, 0.f, 0.f};

    #pragma unroll
    for (int jt = 0; jt < 8; ++jt) {
        #pragma unroll
        for (int kq = 0; kq < 4; ++kq) {
            short8 bfrag = wf[jt * 256 + kq * 64 + lane];
            acc[jt] = __builtin_amdgcn_mfma_f32_16x16x32_bf16(afrag[kq], bfrag,
                                                              acc[jt], 0, 0, 0);
        }
    }
    __syncthreads();    // all afrag reads done; smem reusable

    // Transpose epilogue through LDS -> coalesced 64 B/thread h16 stores.
    // ROUND-4 BUG FIX: each 64 B row segment is 32 shorts = FOUR short8s
    // (previous version copied only two -> half of h16 stale, absmax 2.0).
    const int quad = lane >> 4, nl = lane & 15;
    const int HS = 136;                 // padded row stride (shorts), 272 B
    short* hb = (short*)smem;           // 64 * 136 * 2 = 17408 B
    #pragma unroll
    for (int jt = 0; jt < 8; ++jt) {
        #pragma unroll
        for (int r = 0; r < 4; ++r)
            hb[(w * 16 + quad * 4 + r) * HS + jt * 16 + nl] = f2bf(acc[jt][r]);
    }
    __syncthreads();
    {
        int rrow = tid >> 2, seg = tid & 3;     // row 0..63, 64B segment 0..3
        int node = n0 + rrow;
        if (node < n) {
            const short8* sp = (const short8*)&hb[rrow * HS + seg * 32];
            short8 v0 = sp[0], v1 = sp[1], v2 = sp[2], v3 = sp[3];
            short8* dp = (short8*)(h16 + (size_t)node * DIM + seg * 32);
            dp[0] = v0; dp[1] = v1; dp[2] = v2; dp[3] = v3;
        }
    }
}

__device__ __forceinline__ void ph_expand(
    char* smem, int b, const int* __restrict__ hist, int* __restrict__ base,
    int* __restrict__ cnt, int nbkt, int tid)
{
    int* ls = (int*)smem;
    __syncthreads();
    int v0 = hist[(size_t)(2 * tid)     * nbkt + b];
    int v1 = hist[(size_t)(2 * tid + 1) * nbkt + b];
    int p = v0 + v1;
    ls[tid] = p;
    __syncthreads();
    int inc = p;
    for (int off = 1; off < 256; off <<= 1) {
        int add = (tid >= off) ? ls[tid - off] : 0;
        __syncthreads();
        inc += add;
        ls[tid] = inc;
        __syncthreads();
    }
    int ex = inc - p;                       // exclusive prefix over pairs
    int a0 = b * CAP + ex;
    base[(size_t)(2 * tid)     * nbkt + b] = a0;
    base[(size_t)(2 * tid + 1) * nbkt + b] = a0 + v0;
    if (tid == 255) cnt[b] = inc;           // bucket total
}

__device__ __forceinline__ void ph_scatter(
    char* smem, int g, const int* __restrict__ row, const int* __restrict__ col,
    const float* __restrict__ ew, const int* __restrict__ base,
    int2* __restrict__ srt, int E, int nbkt, int tid)
{
    int* cur = (int*)smem;           // 1024 ints
    __syncthreads();
    for (int b = tid; b < nbkt; b += 256)
        cur[b] = base[(size_t)g * nbkt + b];
    __syncthreads();
    int chunk = (E + HB - 1) / HB;
    int e0 = g * chunk;
    int e1 = e0 + chunk; if (e1 > E) e1 = E;
    for (int e = e0 + tid; e < e1; e += 256) {
        int c = col[e];
        int pos = atomicAdd(&cur[c >> 6], 1);
        srt[pos] = make_int2(((c & 63) << 16) | row[e], __float_as_int(ew[e]));
    }
}

__device__ __forceinline__ void ph_dinv(
    char* smem, int b, const int2* __restrict__ srt, const int* __restrict__ cnt,
    float* __restrict__ dinv, int tid)
{
    float* w64 = (float*)smem;
    __syncthreads();
    if (tid < 64) w64[tid] = 0.f;
    __syncthreads();
    int c = cnt[b];
    int s0 = b * CAP;
    for (int i = tid; i < c; i += 256) {
        int2 v = srt[s0 + i];
        atomicAdd(&w64[(v.x >> 16) & 63], __int_as_float(v.y));
    }
    __syncthreads();
    if (tid < 64)
        dinv[b * 64 + tid] = rsqrtf(1.0f + w64[tid]);   // self-loop weight 1
}

__device__ __forceinline__ void ph_gather(
    char* smem, int b, const int2* __restrict__ srt, const int* __restrict__ cnt,
    const float* __restrict__ dinv, const unsigned short* __restrict__ h16,
    const float* __restrict__ bias, float* __restrict__ out, int n, int tid)
{
    int2*  bufA  = (int2*)smem;                  // 16 KB raw slice
    int2*  bufB  = (int2*)(smem + 16384);        // 16 KB dest-sorted (src,nrm)
    int*   k64   = (int*)(smem + 32768);
    int*   off64 = (int*)(smem + 32768 + 256);
    int*   cur64 = (int*)(smem + 32768 + 512);
    float* di64  = (float*)(smem + 32768 + 768);
    __syncthreads();

    if (tid < 64) { k64[tid] = 0; di64[tid] = dinv[b * 64 + tid]; }
    __syncthreads();

    const int c  = cnt[b];
    const int s0 = b * CAP;
    const int grp = tid >> 4;      // 16 groups of 16 lanes
    const int sub = tid & 15;

    if (c <= CAP) {
        for (int i = tid; i < c; i += 256) {
            int2 v = srt[s0 + i];
            bufA[i] = v;
            atomicAdd(&k64[(v.x >> 16) & 63], 1);
        }
        __syncthreads();
        if (tid == 0) {
            int run = 0;
            #pragma unroll
            for (int d = 0; d < 64; ++d) { off64[d] = run; cur64[d] = run; run += k64[d]; }
        }
        __syncthreads();
        for (int i = tid; i < c; i += 256) {
            int2 v = bufA[i];
            int d   = (v.x >> 16) & 63;
            int src = v.x & 0xFFFF;
            float nrm = dinv[src] * __int_as_float(v.y) * di64[d];
            int p = atomicAdd(&cur64[d], 1);
            bufB[p] = make_int2(src, __float_as_int(nrm));
        }
        __syncthreads();

        #pragma unroll
        for (int dd = 0; dd < 4; ++dd) {
            int d = dd * 16 + grp;
            int dest = b * 64 + d;
            if (dest >= n) continue;
            float di = di64[d];
            short8 sv = *(const short8*)(h16 + (size_t)dest * DIM + sub * 8);
            float s2 = di * di;
            float acc[8];
            #pragma unroll
            for (int k = 0; k < 8; ++k) acc[k] = s2 * bf2f((unsigned short)sv[k]);

            int j  = off64[d];
            int je = j + k64[d];
            for (; j + 3 < je; j += 4) {
                int2 e0 = bufB[j],     e1 = bufB[j + 1];
                int2 e2 = bufB[j + 2], e3 = bufB[j + 3];
                short8 a0 = *(const short8*)(h16 + (size_t)e0.x * DIM + sub * 8);
                short8 a1 = *(const short8*)(h16 + (size_t)e1.x * DIM + sub * 8);
                short8 a2 = *(const short8*)(h16 + (size_t)e2.x * DIM + sub * 8);
                short8 a3 = *(const short8*)(h16 + (size_t)e3.x * DIM + sub * 8);
                float n0 = __int_as_float(e0.y);
                float n1 = __int_as_float(e1.y);
                float n2 = __int_as_float(e2.y);
                float n3 = __int_as_float(e3.y);
                #pragma unroll
                for (int k = 0; k < 8; ++k) {
                    acc[k] = fmaf(n0, bf2f((unsigned short)a0[k]), acc[k]);
                    acc[k] = fmaf(n1, bf2f((unsigned short)a1[k]), acc[k]);
                    acc[k] = fmaf(n2, bf2f((unsigned short)a2[k]), acc[k]);
                    acc[k] = fmaf(n3, bf2f((unsigned short)a3[k]), acc[k]);
                }
            }
            for (; j < je; ++j) {
                int2 e0 = bufB[j];
                float n0 = __int_as_float(e0.y);
                short8 a = *(const short8*)(h16 + (size_t)e0.x * DIM + sub * 8);
                #pragma unroll
                for (int k = 0; k < 8; ++k)
                    acc[k] = fmaf(n0, bf2f((unsigned short)a[k]), acc[k]);
            }

            float4 b0 = *(const float4*)(bias + sub * 8);
            float4 b1 = *(const float4*)(bias + sub * 8 + 4);
            float4 o0, o1;
            o0.x = gelu_exact(acc[0] + b0.x); o0.y = gelu_exact(acc[1] + b0.y);
            o0.z = gelu_exact(acc[2] + b0.z); o0.w = gelu_exact(acc[3] + b0.w);
            o1.x = gelu_exact(acc[4] + b1.x); o1.y = gelu_exact(acc[5] + b1.y);
            o1.z = gelu_exact(acc[6] + b1.z); o1.w = gelu_exact(acc[7] + b1.w);
            float* op = out + (size_t)dest * DIM + sub * 8;
            *(float4*)op       = o0;
            *(float4*)(op + 4) = o1;
        }
    } else {
        // slow correct fallback (statistically unreachable: mean 1024, sd 32)
        #pragma unroll
        for (int dd = 0; dd < 4; ++dd) {
            int d = dd * 16 + grp;
            int dest = b * 64 + d;
            if (dest >= n) continue;
            float di = di64[d];
            short8 sv = *(const short8*)(h16 + (size_t)dest * DIM + sub * 8);
            float s2 = di * di;
            float acc[8];
            #pragma unroll
            for (int k = 0; k < 8; ++k) acc[k] = s2 * bf2f((unsigned short)sv[k]);
            for (int i = 0; i < c; ++i) {
                int2 v = srt[s0 + i];
                if (((v.x >> 16) & 63) != d) continue;
                int src = v.x & 0xFFFF;
                float nrm = dinv[src] * __int_as_float(v.y) * di;
                short8 a = *(const short8*)(h16 + (size_t)src * DIM + sub * 8);
                #pragma unroll
                for (int k = 0; k < 8; ++k)
                    acc[k] = fmaf(nrm, bf2f((unsigned short)a[k]), acc[k]);
            }
            float4 b0 = *(const float4*)(bias + sub * 8);
            float4 b1 = *(const float4*)(bias + sub * 8 + 4);
            float4 o0, o1;
            o0.x = gelu_exact(acc[0] + b0.x); o0.y = gelu_exact(acc[1] + b0.y);
            o0.z = gelu_exact(acc[2] + b0.z); o0.w = gelu_exact(acc[3] + b0.w);
            o1.x = gelu_exact(acc[4] + b1.x); o1.y = gelu_exact(acc[5] + b1.y);
            o1.z = gelu_exact(acc[6] + b1.z); o1.w = gelu_exact(acc[7] + b1.w);
            float* op = out + (size_t)dest * DIM + sub * 8;
            *(float4*)op       = o0;
            *(float4*)(op + 4) = o1;
        }
    }
}

// ========================= cooperative mega-kernel =========================
// All five stages, grid.sync() between dependent phases. Block-stride task
// loops make it correct for any co-resident grid size.
__global__ __launch_bounds__(256) void mega_kernel(
    const float* __restrict__ x, const short* __restrict__ wfrag,
    const float* __restrict__ lnw, const float* __restrict__ lnb,
    unsigned short* __restrict__ h16,
    const int* __restrict__ row, const int* __restrict__ col,
    const float* __restrict__ ew,
    int* __restrict__ hist, int* __restrict__ base, int* __restrict__ cnt,
    int2* __restrict__ srt, float* __restrict__ dinv,
    float* __restrict__ out, const float* __restrict__ bias,
    int n, int E, int nbkt)
{
    __shared__ __align__(16) char smem[SMEM_BYTES];
    cg::grid_group grid = cg::this_grid();
    const int tid = threadIdx.x;
    const int GBt = (n + 63) / 64;

    // Phase A: histogram (tasks 0..HB) + LN+GEMM (tasks HB..HB+GBt)
    for (int t = blockIdx.x; t < HB + GBt; t += gridDim.x) {
        if (t < HB) ph_hist(smem, t, col, hist, E, nbkt, tid);
        else        ph_gemm(smem, t - HB, x, (const short8*)wfrag, lnw, lnb,
                            h16, n, tid);
    }
    grid.sync();
    // Phase B: per-bucket chunk-prefix scan -> base, cnt
    for (int t = blockIdx.x; t < nbkt; t += gridDim.x)
        ph_expand(smem, t, hist, base, cnt, nbkt, tid);
    grid.sync();
    // Phase C: scatter edges into bucket slots
    for (int t = blockIdx.x; t < HB; t += gridDim.x)
        ph_scatter(smem, t, row, col, ew, base, srt, E, nbkt, tid);
    grid.sync();
    // Phase D: per-node dinv
    for (int t = blockIdx.x; t < nbkt; t += gridDim.x)
        ph_dinv(smem, t, srt, cnt, dinv, tid);
    grid.sync();
    // Phase E: fused sort+gather+GELU
    for (int t = blockIdx.x; t < nbkt; t += gridDim.x)
        ph_gather(smem, t, srt, cnt, dinv, h16, bias, out, n, tid);
}

// ===================== non-cooperative fallback wrappers ===================
__global__ __launch_bounds__(256) void k_phaseA(
    const float* __restrict__ x, const short* __restrict__ wfrag,
    const float* __restrict__ lnw, const float* __restrict__ lnb,
    unsigned short* __restrict__ h16, const int* __restrict__ col,
    int* __restrict__ hist, int n, int E, int nbkt)
{
    __shared__ __align__(16) char smem[SMEM_BYTES];
    if ((int)blockIdx.x < HB)
        ph_hist(smem, blockIdx.x, col, hist, E, nbkt, threadIdx.x);
    else
        ph_gemm(smem, blockIdx.x - HB, x, (const short8*)wfrag, lnw, lnb,
                h16, n, threadIdx.x);
}
__global__ __launch_bounds__(256) void k_expand(
    const int* __restrict__ hist, int* __restrict__ base,
    int* __restrict__ cnt, int nbkt)
{
    __shared__ __align__(16) char smem[SMEM_BYTES];
    ph_expand(smem, blockIdx.x, hist, base, cnt, nbkt, threadIdx.x);
}
__global__ __launch_bounds__(256) void k_scatter(
    const int* __restrict__ row, const int* __restrict__ col,
    const float* __restrict__ ew, const int* __restrict__ base,
    int2* __restrict__ srt, int E, int nbkt)
{
    __shared__ __align__(16) char smem[SMEM_BYTES];
    ph_scatter(smem, blockIdx.x, row, col, ew, base, srt, E, nbkt, threadIdx.x);
}
__global__ __launch_bounds__(256) void k_dinv(
    const int2* __restrict__ srt, const int* __restrict__ cnt,
    float* __restrict__ dinv)
{
    __shared__ __align__(16) char smem[SMEM_BYTES];
    ph_dinv(smem, blockIdx.x, srt, cnt, dinv, threadIdx.x);
}
__global__ __launch_bounds__(256) void k_gather(
    const int2* __restrict__ srt, const int* __restrict__ cnt,
    const float* __restrict__ dinv, const unsigned short* __restrict__ h16,
    const float* __restrict__ bias, float* __restrict__ out, int n)
{
    __shared__ __align__(16) char smem[SMEM_BYTES];
    ph_gather(smem, blockIdx.x, srt, cnt, dinv, h16, bias, out, n, threadIdx.x);
}

extern "C" void kernel_launch(void* const* d_in, const int* in_sizes, int n_in,
                              void* d_out, int out_size, void* d_ws, size_t ws_size,
                              hipStream_t stream)
{
    const float* x    = (const float*)d_in[0];
    const int*   ei   = (const int*)d_in[1];
    const float* ew   = (const float*)d_in[2];
    const float* W    = (const float*)d_in[3];
    const float* b    = (const float*)d_in[4];
    const float* ln_w = (const float*)d_in[5];
    const float* ln_b = (const float*)d_in[6];
    float* out = (float*)d_out;

    const int n = in_sizes[0] / DIM;
    const int E = in_sizes[2];
    const int* row  = ei;        // sources
    const int* colp = ei + E;    // targets
    const int nbkt = (n + 63) / 64;

    // workspace layout (16B-aligned first)
    int2*           srt   = (int2*)d_ws;                                // nbkt*CAP
    unsigned short* h16   = (unsigned short*)(srt + (size_t)nbkt * CAP); // n*128
    short*          wfrag = (short*)(h16 + (size_t)n * DIM);            // 16384
    int*            hist  = (int*)(wfrag + 16384);                      // HB*nbkt
    int*            base  = hist + (size_t)HB * nbkt;                   // HB*nbkt
    int*            cnt   = base + (size_t)HB * nbkt;                   // nbkt
    float*          dinv  = (float*)(cnt + nbkt);                       // nbkt*64 (padded)
    // total ~29 MB

    const int GB = (n + 63) / 64;   // gemm tiles

    wconv_kernel<<<8, 256, 0, stream>>>(W, wfrag);

    // cooperative grid size: co-resident blocks (cached; host-only queries)
    static int s_grid = 0;
    if (s_grid == 0) {
        int dev = 0;
        (void)hipGetDevice(&dev);
        int ncu = 256;
        (void)hipDeviceGetAttribute(&ncu, hipDeviceAttributeMultiprocessorCount, dev);
        int bpc = 0;
        (void)hipOccupancyMaxActiveBlocksPerMultiprocessor(
            &bpc, (const void*)mega_kernel, 256, 0);
        if (bpc < 1) bpc = 1;
        long g = (long)ncu * bpc;
        if (g > 1024) g = 1024;   // max tasks per phase is HB+GB; >1024 adds nothing
        if (g < 1) g = 1;
        s_grid = (int)g;
    }

    static bool s_coop_ok = true;
    bool launched = false;
    if (s_coop_ok) {
        void* args[] = {
            (void*)&x, (void*)&wfrag, (void*)&ln_w, (void*)&ln_b, (void*)&h16,
            (void*)&row, (void*)&colp, (void*)&ew,
            (void*)&hist, (void*)&base, (void*)&cnt,
            (void*)&srt, (void*)&dinv, (void*)&out, (void*)&b,
            (void*)&n, (void*)&E, (void*)&nbkt };
        hipError_t err = hipLaunchCooperativeKernel(
            (const void*)mega_kernel, dim3(s_grid), dim3(256), args, 0, stream);
        if (err == hipSuccess) {
            launched = true;
        } else {
            (void)hipGetLastError();   // clear sticky error
            s_coop_ok = false;
        }
    }
    if (!launched) {
        // non-cooperative 5-kernel fallback (same phase code)
        k_phaseA<<<HB + GB, 256, 0, stream>>>(x, wfrag, ln_w, ln_b, h16,
                                              colp, hist, n, E, nbkt);
        k_expand<<<nbkt, 256, 0, stream>>>(hist, base, cnt, nbkt);
        k_scatter<<<HB, 256, 0, stream>>>(row, colp, ew, base, srt, E, nbkt);
        k_dinv<<<nbkt, 256, 0, stream>>>(srt, cnt, dinv);
        k_gather<<<nbkt, 256, 0, stream>>>(srt, cnt, dinv, h16, b, out, n);
    }
}

// Round 6
// 173.666 us; speedup vs baseline: 2.2395x; 2.2395x over previous
//
#include <hip/hip_runtime.h>
#include <math.h>

#define DIM 128
#define LN_EPS 1e-5f
#define HB 512      // edge chunks for histogram/scatter passes
#define CAP 2048    // fixed srt capacity per 64-dest bucket (mean 1024, sd 32)

typedef __attribute__((ext_vector_type(8))) short short8;   // 8 bf16 = 4 VGPR
typedef __attribute__((ext_vector_type(4))) float floatx4;

__device__ __forceinline__ float gelu_exact(float v) {
    return 0.5f * v * (1.0f + erff(v * 0.70710678118654752f));
}
__device__ __forceinline__ float bf2f(unsigned short u) {
    return __uint_as_float(((unsigned)u) << 16);
}
__device__ __forceinline__ short f2bf(float f) {
    unsigned b = __float_as_uint(f);
    return (short)((b + 0x7FFF + ((b >> 16) & 1)) >> 16);  // RNE
}

// ---------------------------------------------------------------------------
// K0: one-time W -> bf16 fragment conversion (fragment-order slots so GEMM
// B-fragments are consecutive 16B loads per lane; stays L2-resident, 32 KB).
// ---------------------------------------------------------------------------
__global__ __launch_bounds__(256) void wconv_kernel(
    const float* __restrict__ W, short* __restrict__ wfrag)
{
    int c = blockIdx.x * 256 + threadIdx.x;   // 0..2047
    int nrow = ((c >> 8) << 4) | (c & 15);                    // jt*16+nloc
    int kb   = (((c >> 6) & 3) << 5) + (((c >> 4) & 3) << 3); // kq*32+quad*8
    const float* wp = W + nrow * DIM + kb;
    float4 w0 = *(const float4*)wp;
    float4 w1 = *(const float4*)(wp + 4);
    short8 p;
    p[0] = f2bf(w0.x); p[1] = f2bf(w0.y); p[2] = f2bf(w0.z); p[3] = f2bf(w0.w);
    p[4] = f2bf(w1.x); p[5] = f2bf(w1.y); p[6] = f2bf(w1.z); p[7] = f2bf(w1.w);
    *(short8*)&wfrag[c * 8] = p;
}

// ---------------------------------------------------------------------------
// K1: blocks [0,HB): per-chunk LDS histogram of dest buckets (no global
// atomics). Blocks [HB, HB+GB): LN + h = xn@W^T via bf16 MFMA, W fragments
// read from global (L2), coalesced transposed h16 epilogue. LDS ~17 KB
// total -> high occupancy for the latency-bound LN/x-load part.
// ---------------------------------------------------------------------------
__global__ __launch_bounds__(256) void gemm_hist_kernel(
    const float* __restrict__ x, const short* __restrict__ wfrag,
    const float* __restrict__ lnw, const float* __restrict__ lnb,
    unsigned short* __restrict__ h16,
    const int* __restrict__ col, int* __restrict__ hist,
    int n, int E, int nbkt)
{
    __shared__ short ubuf[8448];   // 16.5 KB union: axb (8192) / hb (8448) / hist (2048 ints)
    const int tid = threadIdx.x;

    if ((int)blockIdx.x < HB) {
        // ---------------- histogram role ----------------
        int* lh = (int*)ubuf;         // nbkt ints (<= 1024 -> 4 KB)
        for (int b = tid; b < nbkt; b += 256) lh[b] = 0;
        __syncthreads();
        int g = blockIdx.x;
        int chunk = (E + HB - 1) / HB;
        int e0 = g * chunk;
        int e1 = e0 + chunk; if (e1 > E) e1 = E;
        for (int e = e0 + tid; e < e1; e += 256)
            atomicAdd(&lh[col[e] >> 6], 1);          // LDS atomic only
        __syncthreads();
        for (int b = tid; b < nbkt; b += 256)
            hist[(size_t)g * nbkt + b] = lh[b];      // coalesced row write
        return;
    }

    // ---------------- GEMM role ----------------
    const int gb = blockIdx.x - HB;
    const int n0 = gb * 64;
    short* axb = ubuf;               // 16 KB xn bf16 fragments

    // LayerNorm straight from global, 4 threads/node
    {
        int m = tid >> 2, sub = tid & 3;
        int node = n0 + m;
        bool valid = (node < n);
        const float4* xp = (const float4*)(x + (size_t)node * DIM + sub * 32);
        float4 v[8];
        float s = 0.f, ss = 0.f;
        #pragma unroll
        for (int i = 0; i < 8; ++i) {
            v[i] = valid ? xp[i] : make_float4(0.f, 0.f, 0.f, 0.f);
            s  += v[i].x + v[i].y + v[i].z + v[i].w;
            ss += v[i].x * v[i].x + v[i].y * v[i].y + v[i].z * v[i].z + v[i].w * v[i].w;
        }
        s += __shfl_xor(s, 1); ss += __shfl_xor(ss, 1);
        s += __shfl_xor(s, 2); ss += __shfl_xor(ss, 2);
        float mu   = s * (1.0f / 128.0f);
        float var  = ss * (1.0f / 128.0f) - mu * mu;
        float rstd = rsqrtf(var + LN_EPS);

        int mt = m >> 4, mloc = m & 15;
        #pragma unroll
        for (int quad = 0; quad < 4; ++quad) {
            float4 a = v[2 * quad], c4 = v[2 * quad + 1];
            const float4* lw = (const float4*)(lnw + sub * 32 + quad * 8);
            const float4* lb = (const float4*)(lnb + sub * 32 + quad * 8);
            float4 lw0 = lw[0], lw1 = lw[1], lb0 = lb[0], lb1 = lb[1];
            short8 p;
            p[0] = f2bf((a.x  - mu) * rstd * lw0.x + lb0.x);
            p[1] = f2bf((a.y  - mu) * rstd * lw0.y + lb0.y);
            p[2] = f2bf((a.z  - mu) * rstd * lw0.z + lb0.z);
            p[3] = f2bf((a.w  - mu) * rstd * lw0.w + lb0.w);
            p[4] = f2bf((c4.x - mu) * rstd * lw1.x + lb1.x);
            p[5] = f2bf((c4.y - mu) * rstd * lw1.y + lb1.y);
            p[6] = f2bf((c4.z - mu) * rstd * lw1.z + lb1.z);
            p[7] = f2bf((c4.w - mu) * rstd * lw1.w + lb1.w);
            int slot = mt * 256 + sub * 64 + quad * 16 + mloc;
            *(short8*)&axb[slot * 8] = p;
        }
    }
    __syncthreads();

    // MFMA: wave w -> m-tile w, all 8 j-tiles; B fragments from global (L2)
    const int w    = tid >> 6;
    const int lane = tid & 63;
    const short8* wf = (const short8*)wfrag;

    short8 afrag[4];
    #pragma unroll
    for (int kq = 0; kq < 4; ++kq)
        afrag[kq] = *(const short8*)&axb[(w * 256 + kq * 64 + lane) * 8];
    __syncthreads();    // all axb reads done; ubuf reusable as hb

    floatx4 acc[8];
    #pragma unroll
    for (int jt = 0; jt < 8; ++jt) acc[jt] = (floatx4){0.f, 0.f, 0.f, 0.f};

    #pragma unroll
    for (int jt = 0; jt < 8; ++jt) {
        #pragma unroll
        for (int kq = 0; kq < 4; ++kq) {
            short8 bfrag = wf[jt * 256 + kq * 64 + lane];
            acc[jt] = __builtin_amdgcn_mfma_f32_16x16x32_bf16(afrag[kq], bfrag,
                                                              acc[jt], 0, 0, 0);
        }
    }

    // Transposed epilogue through LDS -> coalesced 64 B-burst h16 stores.
    // HS=132 pad: quads land on disjoint bank octets (2-way max = free).
    // Each 64-short row = FOUR short8s per segment pair (round-4 bug: two).
    const int quad = lane >> 4, nl = lane & 15;
    const int HS = 132;                 // padded row stride in shorts
    short* hb = ubuf;                   // 64 * 132 * 2 = 16896 B
    #pragma unroll
    for (int jt = 0; jt < 8; ++jt) {
        #pragma unroll
        for (int r = 0; r < 4; ++r)
            hb[(w * 16 + quad * 4 + r) * HS + jt * 16 + nl] = f2bf(acc[jt][r]);
    }
    __syncthreads();
    {
        int rrow = tid >> 2, seg = tid & 3;     // row 0..63, 64B segment 0..3
        int node = n0 + rrow;
        if (node < n) {
            const short8* sp = (const short8*)&hb[rrow * HS + seg * 32];
            short8 v0 = sp[0], v1 = sp[1], v2 = sp[2], v3 = sp[3];
            short8* dp = (short8*)(h16 + (size_t)node * DIM + seg * 32);
            dp[0] = v0; dp[1] = v1; dp[2] = v2; dp[3] = v3;
        }
    }
}

// ---------------------------------------------------------------------------
// K2: block b scans its bucket's HB=512 chunk counts (pairs per thread) ->
// absolute scatter bases base[g][b] = b*CAP + prefix. Also writes cnt[b].
// ---------------------------------------------------------------------------
__global__ __launch_bounds__(256) void expand_kernel(
    const int* __restrict__ hist, int* __restrict__ base,
    int* __restrict__ cnt, int nbkt)
{
    __shared__ int ls[256];
    const int tid = threadIdx.x;
    const int b = blockIdx.x;

    int v0 = hist[(size_t)(2 * tid)     * nbkt + b];
    int v1 = hist[(size_t)(2 * tid + 1) * nbkt + b];
    int p = v0 + v1;
    ls[tid] = p;
    __syncthreads();
    int inc = p;
    for (int off = 1; off < 256; off <<= 1) {
        int add = (tid >= off) ? ls[tid - off] : 0;
        __syncthreads();
        inc += add;
        ls[tid] = inc;
        __syncthreads();
    }
    int ex = inc - p;                       // exclusive prefix over pairs
    int a0 = b * CAP + ex;
    base[(size_t)(2 * tid)     * nbkt + b] = a0;
    base[(size_t)(2 * tid + 1) * nbkt + b] = a0 + v0;
    if (tid == 255) cnt[b] = inc;           // bucket total
}

// ---------------------------------------------------------------------------
// K3: scatter edges into bucket-slot order via LDS cursors (no global
// atomics). srt[pos] = ((dest&63)<<16 | src, ew)
// ---------------------------------------------------------------------------
__global__ __launch_bounds__(256) void bucket_scatter_kernel(
    const int* __restrict__ row, const int* __restrict__ col,
    const float* __restrict__ ew, const int* __restrict__ base,
    int2* __restrict__ srt, int E, int nbkt)
{
    __shared__ int cur[1024];
    const int tid = threadIdx.x, g = blockIdx.x;
    for (int b = tid; b < nbkt; b += 256)
        cur[b] = base[(size_t)g * nbkt + b];
    __syncthreads();
    int chunk = (E + HB - 1) / HB;
    int e0 = g * chunk;
    int e1 = e0 + chunk; if (e1 > E) e1 = E;
    for (int e = e0 + tid; e < e1; e += 256) {
        int c = col[e];
        int pos = atomicAdd(&cur[c >> 6], 1);
        srt[pos] = make_int2(((c & 63) << 16) | row[e], __float_as_int(ew[e]));
    }
}

// ---------------------------------------------------------------------------
// K4: per-bucket weight sums -> dinv (needed globally before gather since
// edges reference dinv[src] of remote buckets). dinv padded to nbkt*64.
// ---------------------------------------------------------------------------
__global__ __launch_bounds__(256) void dinv_kernel(
    const int2* __restrict__ srt, const int* __restrict__ cnt,
    float* __restrict__ dinv, int n)
{
    __shared__ float w64[64];
    const int tid = threadIdx.x, b = blockIdx.x;
    if (tid < 64) w64[tid] = 0.f;
    __syncthreads();
    int c = cnt[b];
    int s0 = b * CAP;
    for (int i = tid; i < c; i += 256) {
        int2 v = srt[s0 + i];
        atomicAdd(&w64[(v.x >> 16) & 63], __int_as_float(v.y));
    }
    __syncthreads();
    if (tid < 64)
        dinv[b * 64 + tid] = rsqrtf(1.0f + w64[tid]);   // self-loop weight 1
}

// ---------------------------------------------------------------------------
// K5: fused CSR + gather per bucket: stage slice in LDS, count/scan/reorder
// by dest (norm dinv[src]*ew*dinv[dst] folded at reorder), then 16-lane
// groups serially accumulate each dest's edges; self-loop + bias + GELU,
// write out directly.
// ---------------------------------------------------------------------------
__global__ __launch_bounds__(256) void bucket_gather_kernel(
    const int2* __restrict__ srt, const int* __restrict__ cnt,
    const float* __restrict__ dinv, const unsigned short* __restrict__ h16,
    const float* __restrict__ bias, float* __restrict__ out, int n)
{
    __shared__ int2  bufA[CAP];    // 16 KB raw slice
    __shared__ int2  bufB[CAP];    // 16 KB dest-sorted (src, nrm)
    __shared__ int   k64[64], off64[64], cur64[64];
    __shared__ float di64[64];
    const int tid = threadIdx.x, b = blockIdx.x;

    if (tid < 64) { k64[tid] = 0; di64[tid] = dinv[b * 64 + tid]; }
    __syncthreads();

    const int c  = cnt[b];
    const int s0 = b * CAP;
    const int grp = tid >> 4;      // 16 groups of 16 lanes
    const int sub = tid & 15;

    if (c <= CAP) {
        // stage + count
        for (int i = tid; i < c; i += 256) {
            int2 v = srt[s0 + i];
            bufA[i] = v;
            atomicAdd(&k64[(v.x >> 16) & 63], 1);
        }
        __syncthreads();
        if (tid == 0) {
            int run = 0;
            #pragma unroll
            for (int d = 0; d < 64; ++d) { off64[d] = run; cur64[d] = run; run += k64[d]; }
        }
        __syncthreads();
        // reorder with norm folding
        for (int i = tid; i < c; i += 256) {
            int2 v = bufA[i];
            int d   = (v.x >> 16) & 63;
            int src = v.x & 0xFFFF;
            float nrm = dinv[src] * __int_as_float(v.y) * di64[d];
            int p = atomicAdd(&cur64[d], 1);
            bufB[p] = make_int2(src, __float_as_int(nrm));
        }
        __syncthreads();

        // accumulate: group handles 4 dests serially
        #pragma unroll
        for (int dd = 0; dd < 4; ++dd) {
            int d = dd * 16 + grp;
            int dest = b * 64 + d;
            if (dest >= n) continue;
            float di = di64[d];
            short8 sv = *(const short8*)(h16 + (size_t)dest * DIM + sub * 8);
            float s2 = di * di;
            float acc[8];
            #pragma unroll
            for (int k = 0; k < 8; ++k) acc[k] = s2 * bf2f((unsigned short)sv[k]);

            int j  = off64[d];
            int je = j + k64[d];
            for (; j + 3 < je; j += 4) {
                int2 e0 = bufB[j],     e1 = bufB[j + 1];
                int2 e2 = bufB[j + 2], e3 = bufB[j + 3];
                short8 a0 = *(const short8*)(h16 + (size_t)e0.x * DIM + sub * 8);
                short8 a1 = *(const short8*)(h16 + (size_t)e1.x * DIM + sub * 8);
                short8 a2 = *(const short8*)(h16 + (size_t)e2.x * DIM + sub * 8);
                short8 a3 = *(const short8*)(h16 + (size_t)e3.x * DIM + sub * 8);
                float n0 = __int_as_float(e0.y);
                float n1 = __int_as_float(e1.y);
                float n2 = __int_as_float(e2.y);
                float n3 = __int_as_float(e3.y);
                #pragma unroll
                for (int k = 0; k < 8; ++k) {
                    acc[k] = fmaf(n0, bf2f((unsigned short)a0[k]), acc[k]);
                    acc[k] = fmaf(n1, bf2f((unsigned short)a1[k]), acc[k]);
                    acc[k] = fmaf(n2, bf2f((unsigned short)a2[k]), acc[k]);
                    acc[k] = fmaf(n3, bf2f((unsigned short)a3[k]), acc[k]);
                }
            }
            for (; j < je; ++j) {
                int2 e0 = bufB[j];
                float n0 = __int_as_float(e0.y);
                short8 a = *(const short8*)(h16 + (size_t)e0.x * DIM + sub * 8);
                #pragma unroll
                for (int k = 0; k < 8; ++k)
                    acc[k] = fmaf(n0, bf2f((unsigned short)a[k]), acc[k]);
            }

            float4 b0 = *(const float4*)(bias + sub * 8);
            float4 b1 = *(const float4*)(bias + sub * 8 + 4);
            float4 o0, o1;
            o0.x = gelu_exact(acc[0] + b0.x); o0.y = gelu_exact(acc[1] + b0.y);
            o0.z = gelu_exact(acc[2] + b0.z); o0.w = gelu_exact(acc[3] + b0.w);
            o1.x = gelu_exact(acc[4] + b1.x); o1.y = gelu_exact(acc[5] + b1.y);
            o1.z = gelu_exact(acc[6] + b1.z); o1.w = gelu_exact(acc[7] + b1.w);
            float* op = out + (size_t)dest * DIM + sub * 8;
            *(float4*)op       = o0;
            *(float4*)(op + 4) = o1;
        }
    } else {
        // slow correct fallback (statistically unreachable: mean 1024, sd 32)
        #pragma unroll
        for (int dd = 0; dd < 4; ++dd) {
            int d = dd * 16 + grp;
            int dest = b * 64 + d;
            if (dest >= n) continue;
            float di = di64[d];
            short8 sv = *(const short8*)(h16 + (size_t)dest * DIM + sub * 8);
            float s2 = di * di;
            float acc[8];
            #pragma unroll
            for (int k = 0; k < 8; ++k) acc[k] = s2 * bf2f((unsigned short)sv[k]);
            for (int i = 0; i < c; ++i) {
                int2 v = srt[s0 + i];
                if (((v.x >> 16) & 63) != d) continue;
                int src = v.x & 0xFFFF;
                float nrm = dinv[src] * __int_as_float(v.y) * di;
                short8 a = *(const short8*)(h16 + (size_t)src * DIM + sub * 8);
                #pragma unroll
                for (int k = 0; k < 8; ++k)
                    acc[k] = fmaf(nrm, bf2f((unsigned short)a[k]), acc[k]);
            }
            float4 b0 = *(const float4*)(bias + sub * 8);
            float4 b1 = *(const float4*)(bias + sub * 8 + 4);
            float4 o0, o1;
            o0.x = gelu_exact(acc[0] + b0.x); o0.y = gelu_exact(acc[1] + b0.y);
            o0.z = gelu_exact(acc[2] + b0.z); o0.w = gelu_exact(acc[3] + b0.w);
            o1.x = gelu_exact(acc[4] + b1.x); o1.y = gelu_exact(acc[5] + b1.y);
            o1.z = gelu_exact(acc[6] + b1.z); o1.w = gelu_exact(acc[7] + b1.w);
            float* op = out + (size_t)dest * DIM + sub * 8;
            *(float4*)op       = o0;
            *(float4*)(op + 4) = o1;
        }
    }
}

extern "C" void kernel_launch(void* const* d_in, const int* in_sizes, int n_in,
                              void* d_out, int out_size, void* d_ws, size_t ws_size,
                              hipStream_t stream)
{
    const float* x    = (const float*)d_in[0];
    const int*   ei   = (const int*)d_in[1];
    const float* ew   = (const float*)d_in[2];
    const float* W    = (const float*)d_in[3];
    const float* b    = (const float*)d_in[4];
    const float* ln_w = (const float*)d_in[5];
    const float* ln_b = (const float*)d_in[6];
    float* out = (float*)d_out;

    const int n = in_sizes[0] / DIM;
    const int E = in_sizes[2];
    const int* row  = ei;        // sources
    const int* colp = ei + E;    // targets
    const int nbkt = (n + 63) / 64;

    // workspace layout (16B-aligned first)
    int2*           srt   = (int2*)d_ws;                                 // nbkt*CAP
    unsigned short* h16   = (unsigned short*)(srt + (size_t)nbkt * CAP); // n*128
    short*          wfrag = (short*)(h16 + (size_t)n * DIM);             // 16384
    int*            hist  = (int*)(wfrag + 16384);                       // HB*nbkt
    int*            base  = hist + (size_t)HB * nbkt;                    // HB*nbkt
    int*            cnt   = base + (size_t)HB * nbkt;                    // nbkt
    float*          dinv  = (float*)(cnt + nbkt);                        // nbkt*64 (padded)
    // total ~29 MB

    const int GB = (n + 63) / 64;   // gemm tiles

    wconv_kernel<<<8, 256, 0, stream>>>(W, wfrag);
    gemm_hist_kernel<<<HB + GB, 256, 0, stream>>>(x, wfrag, ln_w, ln_b, h16,
                                                  colp, hist, n, E, nbkt);
    expand_kernel<<<nbkt, 256, 0, stream>>>(hist, base, cnt, nbkt);
    bucket_scatter_kernel<<<HB, 256, 0, stream>>>(row, colp, ew, base, srt, E, nbkt);
    dinv_kernel<<<nbkt, 256, 0, stream>>>(srt, cnt, dinv, n);
    bucket_gather_kernel<<<nbkt, 256, 0, stream>>>(srt, cnt, dinv, h16, b, out, n);
}